// Round 2
// baseline (570.746 us; speedup 1.0000x reference)
//
#include <hip/hip_runtime.h>
#include <math.h>

// ---------------------------------------------------------------------------
// SpectralConv3d + Chebyshev-Fourier correction, fp32, pruned separable DFTs.
// B=4, C=O=32, H=W=D=64. Modes: kx,ky in {0..11,52..63} (24), kz in {0..11}.
// Round 2: address-math-free inner loops (immediate-offset LDS, replicated
// twiddle tables), d-symmetry halves z-stage FLOPs.
// ---------------------------------------------------------------------------

static __device__ __forceinline__ void fill_base(float2* twb, int tid, int nthr) {
    // twb[m] = (cos(2 pi m / 64), sin(2 pi m / 64))
    for (int m = tid; m < 64; m += nthr) {
        float s, c;
        sincosf((float)m * 0.09817477042468103f, &s, &c);
        twb[m] = make_float2(c, s);
    }
}

static __device__ __forceinline__ void fill_mode(float2* twm, const float2* twb,
                                                 int tid, int nthr) {
    // twm[a*64+p] = (cos, sin)(2 pi kyv_a p / 64), kyv = a<12 ? a : a+40
    for (int i = tid; i < 24 * 64; i += nthr) {
        int a = i >> 6, p = i & 63;
        int kv = a < 12 ? a : a + 40;
        twm[i] = twb[(kv * p) & 63];
    }
}

// ---------------------------------------------------------------------------
// Kernel 1: fused forward DFT along D (64->12, via real-input symmetry) and
// W (64->24). grid = B*C*H = 8192 blocks, 384 threads.
// X2[(bc*64+h)*288 + a*12 + kz]
// ---------------------------------------------------------------------------
__global__ __launch_bounds__(384) void k_fwd_zy(const float* __restrict__ x,
                                                float2* __restrict__ X2) {
    __shared__ union {
        float  xt[64 * 68];              // [w][d] pad 68
        float2 uvb[32 * 64];             // rows 0..30: (u,v) for d=1..31; row31=(x0,x32)
    } U;
    __shared__ float2 twz[32 * 12];      // [d][kz] = (cos,sin)(kz*d)
    __shared__ float2 twm[24 * 64];      // [a][w]
    __shared__ float2 z1[64 * 14];       // [w][kz] pad 14
    __shared__ float2 twb[64];
    const int tid = threadIdx.x;
    const int blk = blockIdx.x;          // (b*32+c)*64 + h

    // stage x row -> LDS (1024 float4)
    const float4* xr4 = (const float4*)(x + (size_t)blk * 4096);
    float4 ld[3]; int li[3]; int nld = 0;
    for (int i4 = tid; i4 < 1024; i4 += 384) { li[nld] = i4; ld[nld] = xr4[i4]; ++nld; }
    fill_base(twb, tid, 384);
    for (int k = 0; k < nld; ++k) {
        int i4 = li[k], w = i4 >> 4, d4 = (i4 & 15) << 2;
        *(float4*)&U.xt[w * 68 + d4] = ld[k];
    }
    __syncthreads();

    // fill twiddle tables (reads twb)
    for (int i = tid; i < 32 * 12; i += 384) {
        int d = i / 12, kz = i - d * 12;
        twz[i] = twb[(kz * d) & 63];
    }
    fill_mode(twm, twb, tid, 384);

    // u/v pass: read xt into regs, then overwrite union with uv
    float2 uvv[6]; int ur[6], uw[6]; int nuv = 0;
    for (int i = tid; i < 2048; i += 384) {
        int d = i & 31, w = i >> 5;
        float u, v; int r;
        if (d == 0) { u = U.xt[w * 68]; v = U.xt[w * 68 + 32]; r = 31; }
        else {
            float a = U.xt[w * 68 + d], b = U.xt[w * 68 + 64 - d];
            u = a + b; v = a - b; r = d - 1;
        }
        ur[nuv] = r; uw[nuv] = w; uvv[nuv] = make_float2(u, v); ++nuv;
    }
    __syncthreads();
    for (int k = 0; k < nuv; ++k) U.uvb[ur[k] * 64 + uw[k]] = uvv[k];
    __syncthreads();

    // z-stage: w = lane, q = wave (0..5) -> kz {2q, 2q+1}
    {
        const int w = tid & 63, q = tid >> 6;
        float2 p = U.uvb[31 * 64 + w];   // (x0, x32)
        float re0 = p.x + p.y;           // kz = 2q even: +x32
        float re1 = p.x - p.y;           // kz = 2q+1 odd: -x32
        float im0 = 0.f, im1 = 0.f;
        const float2* uvp = &U.uvb[w];
        #pragma unroll
        for (int d = 1; d <= 31; ++d) {
            float2 uvd = uvp[(d - 1) * 64];
            float4 t = *(const float4*)&twz[d * 12 + 2 * q];   // (c0,s0,c1,s1)
            re0 += uvd.x * t.x; im0 -= uvd.y * t.y;
            re1 += uvd.x * t.z; im1 -= uvd.y * t.w;
        }
        *(float4*)&z1[w * 14 + 2 * q] = make_float4(re0, im0, re1, im1);
    }
    __syncthreads();

    // y-stage: one output (a,kz) per thread, 288 active
    if (tid < 288) {
        const int a = tid / 12, kz = tid - (tid / 12) * 12;
        const float2* zp = &z1[kz];
        const float2* tp = &twm[a * 64];
        float2 acc = make_float2(0.f, 0.f);
        #pragma unroll
        for (int w = 0; w < 64; ++w) {
            float2 z = zp[w * 14];
            float2 t = tp[w];
            acc.x += z.x * t.x + z.y * t.y;   // z * conj(t)
            acc.y += z.y * t.x - z.x * t.y;
        }
        X2[(size_t)blk * 288 + tid] = acc;
    }
}

// ---------------------------------------------------------------------------
// Kernel 2: forward DFT along H (64->24). grid = B*C*24 = 3072, 288 threads.
// X3[bc*6912 + ax*288 + ay*12 + kz]
// ---------------------------------------------------------------------------
__global__ __launch_bounds__(288) void k_fwd_x(const float2* __restrict__ X2,
                                               float2* __restrict__ X3) {
    __shared__ float2 s2[64 * 14];       // [h][kz]
    __shared__ float2 twm[24 * 64];
    __shared__ float2 twb[64];
    const int tid = threadIdx.x;
    const int ay = blockIdx.x % 24, bc = blockIdx.x / 24;
    const float2* src = X2 + (size_t)bc * (64 * 288) + ay * 12;
    for (int j = tid; j < 768; j += 288) {
        int h = j / 12, kz = j - h * 12;
        s2[h * 14 + kz] = src[h * 288 + kz];
    }
    fill_base(twb, tid, 288);
    __syncthreads();
    fill_mode(twm, twb, tid, 288);
    __syncthreads();
    const int ax = tid / 12, kz = tid - (tid / 12) * 12;
    const float2* zp = &s2[kz];
    const float2* tp = &twm[ax * 64];
    float2 acc = make_float2(0.f, 0.f);
    #pragma unroll
    for (int h = 0; h < 64; ++h) {
        float2 z = zp[h * 14];
        float2 t = tp[h];
        acc.x += z.x * t.x + z.y * t.y;
        acc.y += z.y * t.x - z.x * t.y;
    }
    X3[(size_t)bc * 6912 + ax * 288 + ay * 12 + kz] = acc;
}

// ---------------------------------------------------------------------------
// Kernel 3: mode mixing (unchanged from round 1).
// ---------------------------------------------------------------------------
__global__ __launch_bounds__(384) void k_mix(const float2* __restrict__ X3,
                                             float2* __restrict__ F,
        const float* __restrict__ w1re, const float* __restrict__ w1im,
        const float* __restrict__ w2re, const float* __restrict__ w2im,
        const float* __restrict__ w3re, const float* __restrict__ w3im,
        const float* __restrict__ w4re, const float* __restrict__ w4im) {
    __shared__ float2 xs[128 * 12];
    const int tid = threadIdx.x;
    const int blk = blockIdx.x;
    const int ax = blk / 24, ay = blk % 24;
    const int cx = ax >= 12 ? 1 : 0, cy = ay >= 12 ? 1 : 0;
    const int m1 = ax - cx * 12, m2 = ay - cy * 12;
    const int sel = cx + cy * 2;
    const float* wre = sel == 0 ? w1re : sel == 1 ? w2re : sel == 2 ? w3re : w4re;
    const float* wim = sel == 0 ? w1im : sel == 1 ? w2im : sel == 2 ? w3im : w4im;
    const size_t moff = (size_t)ax * 288 + (size_t)ay * 12;
    for (int i = tid; i < 1536; i += 384) {
        int bi = i / 12, kz = i - bi * 12;
        xs[i] = X3[(size_t)bi * 6912 + moff + kz];
    }
    __syncthreads();
    const int o = tid / 12, kz = tid - (tid / 12) * 12;
    const int wbase = o * 1728 + m1 * 144 + m2 * 12 + kz;
    float2 A0 = make_float2(0.f, 0.f), A1 = A0, A2 = A0, A3 = A0;
    for (int i = 0; i < 32; ++i) {
        float wr = wre[i * 55296 + wbase];
        float wi = wim[i * 55296 + wbase];
        float2 x0 = xs[i * 12 + kz];
        float2 x1 = xs[(32 + i) * 12 + kz];
        float2 x2 = xs[(64 + i) * 12 + kz];
        float2 x3 = xs[(96 + i) * 12 + kz];
        A0.x += x0.x * wr - x0.y * wi; A0.y += x0.x * wi + x0.y * wr;
        A1.x += x1.x * wr - x1.y * wi; A1.y += x1.x * wi + x1.y * wr;
        A2.x += x2.x * wr - x2.y * wi; A2.y += x2.x * wi + x2.y * wr;
        A3.x += x3.x * wr - x3.y * wi; A3.y += x3.x * wi + x3.y * wr;
    }
    F[(size_t)(0 * 32 + o) * 6912 + moff + kz] = A0;
    F[(size_t)(1 * 32 + o) * 6912 + moff + kz] = A1;
    F[(size_t)(2 * 32 + o) * 6912 + moff + kz] = A2;
    F[(size_t)(3 * 32 + o) * 6912 + moff + kz] = A3;
}

// ---------------------------------------------------------------------------
// Kernel 4: inverse DFT along H (24->64). grid = B*O*24 = 3072, 384 threads
// (2 outputs each). Y1[(bo*64+h)*288 + ay*12 + kz]
// ---------------------------------------------------------------------------
__global__ __launch_bounds__(384) void k_inv_x(const float2* __restrict__ F,
                                               float2* __restrict__ Y1) {
    __shared__ float2 fs[24 * 14];       // [ax][kz]
    __shared__ float2 twm[24 * 64];
    __shared__ float2 twb[64];
    const int tid = threadIdx.x;
    const int ay = blockIdx.x % 24, bo = blockIdx.x / 24;
    const float2* src = F + (size_t)bo * 6912 + ay * 12;
    for (int j = tid; j < 288; j += 384) {
        int ax = j / 12, kz = j - ax * 12;
        fs[ax * 14 + kz] = src[ax * 288 + kz];
    }
    fill_base(twb, tid, 384);
    __syncthreads();
    fill_mode(twm, twb, tid, 384);
    __syncthreads();
    float2* dst = Y1 + (size_t)bo * (64 * 288) + ay * 12;
    #pragma unroll
    for (int r = 0; r < 2; ++r) {
        int idx = r * 384 + tid;         // 0..767 = (hh, kz)
        int hh = idx / 12, kz = idx - (idx / 12) * 12;
        const float2* fp = &fs[kz];
        float2 acc = make_float2(0.f, 0.f);
        #pragma unroll
        for (int ax = 0; ax < 24; ++ax) {
            float2 f = fp[ax * 14];
            float2 t = twm[ax * 64 + hh];
            acc.x += f.x * t.x - f.y * t.y;   // f * t (inverse)
            acc.y += f.x * t.y + f.y * t.x;
        }
        dst[hh * 288 + kz] = acc;
    }
}

// ---------------------------------------------------------------------------
// Kernel 5: CFT branch (unchanged from round 1).
// ---------------------------------------------------------------------------
__global__ __launch_bounds__(256) void k_cft(const float* __restrict__ x,
                                             float* __restrict__ cft) {
    __shared__ float2 tw[64];
    __shared__ float red[3 * 64 * 18];
    const int tid = threadIdx.x;
    const int blk = blockIdx.x;          // b*32 + c
    const int d = tid & 63, q = tid >> 6;
    fill_base(tw, tid, 256);
    __syncthreads();
    float aR[3][3] = {{0.f}}, aI[3][3] = {{0.f}};
    const float* xb = x + (size_t)blk * 262144;
    for (int wi = 0; wi < 16; ++wi) {
        const int w = q * 16 + wi;
        float c0 = 0.f, c1 = 0.f, c2 = 0.f;
        #pragma unroll
        for (int s = 0; s < 8; ++s) {
            float xv = xb[(size_t)(s * 64 + w) * 64 + d];
            float t = (2.0f * (float)s - 7.0f) * (1.0f / 7.0f);
            c0 += xv;
            c1 += xv * t;
            c2 += xv * (2.0f * t * t - 1.0f);
        }
        c0 *= 0.125f; c1 *= 0.125f; c2 *= 0.125f;
        #pragma unroll
        for (int f = 0; f < 3; ++f) {
            float2 t = tw[(f * w) & 63];
            aR[0][f] += c0 * t.x; aI[0][f] -= c0 * t.y;
            aR[1][f] += c1 * t.x; aI[1][f] -= c1 * t.y;
            aR[2][f] += c2 * t.x; aI[2][f] -= c2 * t.y;
        }
    }
    if (q > 0) {
        float* dst = &red[((q - 1) * 64 + d) * 18];
        #pragma unroll
        for (int k = 0; k < 3; ++k)
            #pragma unroll
            for (int f = 0; f < 3; ++f) {
                dst[k * 6 + f * 2]     = aR[k][f];
                dst[k * 6 + f * 2 + 1] = aI[k][f];
            }
    }
    __syncthreads();
    if (q == 0) {
        #pragma unroll
        for (int qq = 0; qq < 3; ++qq) {
            const float* sr = &red[(qq * 64 + d) * 18];
            #pragma unroll
            for (int k = 0; k < 3; ++k)
                #pragma unroll
                for (int f = 0; f < 3; ++f) {
                    aR[k][f] += sr[k * 6 + f * 2];
                    aI[k][f] += sr[k * 6 + f * 2 + 1];
                }
        }
        const int b = blk >> 5, c = blk & 31;
        float* dst = cft + (size_t)(b * 64 + d) * 576 + c * 18;
        #pragma unroll
        for (int k = 0; k < 3; ++k)
            #pragma unroll
            for (int f = 0; f < 3; ++f) {
                dst[k * 6 + f * 2]     = aR[k][f];
                dst[k * 6 + f * 2 + 1] = aI[k][f];
            }
    }
}

// ---------------------------------------------------------------------------
// Kernel 6: MLP 576->128 (exact GeLU) ->32 (unchanged from round 1).
// ---------------------------------------------------------------------------
__global__ __launch_bounds__(128) void k_mlp(const float* __restrict__ cft,
                                             const float* __restrict__ w1,
                                             const float* __restrict__ b1,
                                             const float* __restrict__ w2,
                                             const float* __restrict__ b2,
                                             const float* __restrict__ cs,
                                             float* __restrict__ corr) {
    __shared__ float row[576];
    __shared__ float hbuf[128];
    const int n = blockIdx.x;            // b*64 + d
    const int tid = threadIdx.x;
    for (int i = tid; i < 576; i += 128) row[i] = cft[(size_t)n * 576 + i];
    __syncthreads();
    float acc = b1[tid];
    for (int k = 0; k < 576; ++k) acc += row[k] * w1[k * 128 + tid];
    hbuf[tid] = 0.5f * acc * (1.0f + erff(acc * 0.70710678118654752f));
    __syncthreads();
    if (tid < 32) {
        float a2 = b2[tid];
        for (int k = 0; k < 128; ++k) a2 += hbuf[k] * w2[k * 32 + tid];
        const int b = n >> 6, d = n & 63;
        corr[(b * 32 + tid) * 64 + d] = a2 * cs[0];
    }
}

// ---------------------------------------------------------------------------
// Kernel 7: fused inverse DFT along W (24->64) and D (12->64, c2r with c_kz),
// + correction add. grid = B*O*H = 8192, 384 threads.
// ---------------------------------------------------------------------------
__global__ __launch_bounds__(384) void k_inv_yz(const float2* __restrict__ Y1,
                                                const float* __restrict__ corr,
                                                float* __restrict__ out) {
    __shared__ float2 y1s[24 * 16];      // [a][kz] pad 16 (b128-aligned)
    __shared__ float2 y2[64 * 14];       // [w][kz] pad 14
    __shared__ float2 twm[24 * 64];      // [a][w]
    __shared__ float2 twb[64];
    __shared__ float corrl[64];
    const int tid = threadIdx.x;
    const int blk = blockIdx.x;          // (b*32+o)*64 + h
    const int bo = blk >> 6;
    for (int j = tid; j < 288; j += 384) {
        int a = j / 12, kz = j - a * 12;
        y1s[a * 16 + kz] = Y1[(size_t)blk * 288 + j];
    }
    if (tid < 64) corrl[tid] = corr[bo * 64 + tid];
    fill_base(twb, tid, 384);
    __syncthreads();
    fill_mode(twm, twb, tid, 384);
    __syncthreads();
    // stage A: W inverse; w = lane, q = wave -> kz {2q, 2q+1}
    {
        const int w = tid & 63, q = tid >> 6;
        float a0x = 0.f, a0y = 0.f, a1x = 0.f, a1y = 0.f;
        #pragma unroll
        for (int a = 0; a < 24; ++a) {
            float4 f = *(const float4*)&y1s[a * 16 + 2 * q];  // (f0r,f0i,f1r,f1i)
            float2 t = twm[a * 64 + w];
            a0x += f.x * t.x - f.y * t.y;  a0y += f.x * t.y + f.y * t.x;
            a1x += f.z * t.x - f.w * t.y;  a1y += f.z * t.y + f.w * t.x;
        }
        *(float4*)&y2[w * 14 + 2 * q] = make_float4(a0x, a0y, a1x, a1y);
    }
    // per-thread D twiddles (scaled), fixed d = lane
    const int d = tid & 63, wg = tid >> 6;     // wg in 0..5
    float ct[12], st[12];
    #pragma unroll
    for (int kz = 0; kz < 12; ++kz) {
        float2 t = twb[(kz * d) & 63];
        float sc = (kz == 0 ? 1.0f : 2.0f) * (1.0f / 262144.0f);
        ct[kz] = t.x * sc;
        st[kz] = t.y * sc;
    }
    const float cv = corrl[d];
    __syncthreads();
    float* orow = out + (size_t)blk * 4096;
    #pragma unroll
    for (int j = 0; j < 11; ++j) {
        int w = wg + 6 * j;
        if (w < 64) {
            const float4* yp = (const float4*)&y2[w * 14];
            float s = cv;
            #pragma unroll
            for (int kk = 0; kk < 6; ++kk) {
                float4 yv = yp[kk];            // kz = 2kk, 2kk+1
                s += yv.x * ct[2 * kk]     - yv.y * st[2 * kk];
                s += yv.z * ct[2 * kk + 1] - yv.w * st[2 * kk + 1];
            }
            orow[w * 64 + d] = s;
        }
    }
}

// ---------------------------------------------------------------------------
extern "C" void kernel_launch(void* const* d_in, const int* in_sizes, int n_in,
                              void* d_out, int out_size, void* d_ws, size_t ws_size,
                              hipStream_t stream) {
    const float* x    = (const float*)d_in[0];
    const float* w1re = (const float*)d_in[1];
    const float* w1im = (const float*)d_in[2];
    const float* w2re = (const float*)d_in[3];
    const float* w2im = (const float*)d_in[4];
    const float* w3re = (const float*)d_in[5];
    const float* w3im = (const float*)d_in[6];
    const float* w4re = (const float*)d_in[7];
    const float* w4im = (const float*)d_in[8];
    const float* mw1  = (const float*)d_in[9];
    const float* mb1  = (const float*)d_in[10];
    const float* mw2  = (const float*)d_in[11];
    const float* mb2  = (const float*)d_in[12];
    const float* cs   = (const float*)d_in[13];
    float* out = (float*)d_out;

    char* ws = (char*)d_ws;
    float2* X2   = (float2*)(ws);                 // 18,874,368 B (reused as Y1)
    float2* X3   = (float2*)(ws + 18874368);      //  7,077,888 B
    float2* F    = (float2*)(ws + 25952256);      //  7,077,888 B
    float*  cft  = (float*) (ws + 33030144);      //    589,824 B
    float*  corr = (float*) (ws + 33619968);      //     32,768 B
    float2* Y1   = X2;                            // X2 dead after k_fwd_x

    hipLaunchKernelGGL(k_fwd_zy, dim3(8192), dim3(384), 0, stream, x, X2);
    hipLaunchKernelGGL(k_fwd_x,  dim3(3072), dim3(288), 0, stream, X2, X3);
    hipLaunchKernelGGL(k_mix,    dim3(576),  dim3(384), 0, stream, X3, F,
                       w1re, w1im, w2re, w2im, w3re, w3im, w4re, w4im);
    hipLaunchKernelGGL(k_inv_x,  dim3(3072), dim3(384), 0, stream, F, Y1);
    hipLaunchKernelGGL(k_cft,    dim3(128),  dim3(256), 0, stream, x, cft);
    hipLaunchKernelGGL(k_mlp,    dim3(256),  dim3(128), 0, stream,
                       cft, mw1, mb1, mw2, mb2, cs, corr);
    hipLaunchKernelGGL(k_inv_yz, dim3(8192), dim3(384), 0, stream, Y1, corr, out);
}